// Round 18
// baseline (619.422 us; speedup 1.0000x reference)
//
#include <hip/hip_runtime.h>
#include <hip/hip_bf16.h>

#define N_NODES 50000
#define N_EDGES 1600000
#define IN_CH 64
#define NUM_HID 256
#define NUM_CLASSES 16
#define NUM_GRAPHS 512
#define NBS 196  // ceil(N_NODES/256)

typedef short bf16x8 __attribute__((ext_vector_type(8)));
typedef float f32x4 __attribute__((ext_vector_type(4)));

#if __has_builtin(__builtin_amdgcn_rcpf)
#define RCPF(x) __builtin_amdgcn_rcpf(x)
#else
#define RCPF(x) (1.0f / (x))
#endif

__device__ inline unsigned short f2b(float f) {
    unsigned int u = __float_as_uint(f);
    unsigned int r = (u + 0x7FFF + ((u >> 16) & 1)) >> 16;
    return (unsigned short)r;
}
__device__ inline float b2f(unsigned short u) {
    return __uint_as_float(((unsigned int)u) << 16);
}

// ---------------- preprocessing ----------------
__global__ void prep_w_kernel(const float* __restrict__ wf1, const float* __restrict__ ws1,
                              const float* __restrict__ wf2, const float* __restrict__ ws2,
                              unsigned short* __restrict__ wb1, unsigned short* __restrict__ wb2) {
    int i = blockIdx.x * 256 + threadIdx.x;
    if (i >= 128 * 160) return;
    int r = i / 160, k = i - r * 160;
    wb1[i] = f2b(r < 64 ? wf1[r * 160 + k] : ws1[(r - 64) * 160 + k]);
    wb2[i] = f2b(r < 64 ? wf2[r * 160 + k] : ws2[(r - 64) * 160 + k]);
}

__global__ void prep_x_kernel(const float4* __restrict__ x, unsigned short* __restrict__ xb) {
    int i = blockIdx.x * 256 + threadIdx.x;
    if (i >= N_NODES * 16) return;
    float4 v = x[i];
    ushort4 u; u.x = f2b(v.x); u.y = f2b(v.y); u.z = f2b(v.z); u.w = f2b(v.w);
    *(ushort4*)(xb + i * 4) = u;
}

__global__ void hist_kernel(const int* __restrict__ ei, int* __restrict__ cnt) {
    int i = blockIdx.x * 256 + threadIdx.x;
    if (i < N_EDGES) atomicAdd(&cnt[ei[N_EDGES + i]], 1);
}

__global__ void bsum_kernel(const int* __restrict__ cnt, int* __restrict__ bsum) {
    __shared__ int sm[256];
    int i = blockIdx.x * 256 + threadIdx.x;
    sm[threadIdx.x] = (i < N_NODES) ? cnt[i] : 0;
    __syncthreads();
    for (int off = 128; off > 0; off >>= 1) {
        if (threadIdx.x < off) sm[threadIdx.x] += sm[threadIdx.x + off];
        __syncthreads();
    }
    if (threadIdx.x == 0) bsum[blockIdx.x] = sm[0];
}

__global__ void bscan_kernel(const int* __restrict__ bsum, int* __restrict__ boffs) {
    __shared__ int sm[256];
    int t = threadIdx.x;
    int v = (t < NBS) ? bsum[t] : 0;
    sm[t] = v; __syncthreads();
    for (int off = 1; off < 256; off <<= 1) {
        int u = (t >= off) ? sm[t - off] : 0;
        __syncthreads();
        sm[t] += u;
        __syncthreads();
    }
    if (t < NBS) boffs[t] = sm[t] - v;  // exclusive
}

__global__ void apply_kernel(const int* __restrict__ cnt, const int* __restrict__ boffs,
                             int* __restrict__ cursor, float* __restrict__ invdeg) {
    __shared__ int sm[256];
    int t = threadIdx.x, i = blockIdx.x * 256 + t;
    int c = (i < N_NODES) ? cnt[i] : 0;
    sm[t] = c; __syncthreads();
    for (int off = 1; off < 256; off <<= 1) {
        int u = (t >= off) ? sm[t - off] : 0;
        __syncthreads();
        sm[t] += u;
        __syncthreads();
    }
    if (i < N_NODES) {
        cursor[i] = boffs[blockIdx.x] + sm[t] - c;
        invdeg[i] = 1.0f / fmaxf((float)c, 1.0f);
    }
}

// scatter: light — only sed (src,dst) + eidx, 12B/edge scattered
__global__ void scatter_kernel(const int* __restrict__ ei, int* __restrict__ cursor,
                               int2* __restrict__ sed, int* __restrict__ eidx) {
    int e = blockIdx.x * 256 + threadIdx.x;
    if (e >= N_EDGES) return;
    int s = ei[e], d = ei[N_EDGES + e];
    int p = atomicAdd(&cursor[d], 1);
    sed[p] = make_int2(s, d);
    eidx[p] = e;
}

// ---------------- edge pass: WAVE-PRIVATE 16-edge tiles, zero main-loop barriers ----
// B (both matrices) in LDS, fragment-major (read-only after one-time stage).
// Each wave: gather A-frags to regs (x/h from bf16 buf; edge_attr f32 via eidx) ->
// 40 MFMA (B from LDS) -> act in regs -> ballot run-reduce -> one 64-lane atomic/run.
__global__ __launch_bounds__(256, 2)
void edge_mfma(const unsigned short* __restrict__ xb,
               const int2* __restrict__ sed, const int* __restrict__ eidx,
               const float* __restrict__ ea,
               const unsigned short* __restrict__ wb,
               const float* __restrict__ bfv, const float* __restrict__ bsv,
               float* __restrict__ agg)
{
    // Bl[frag=mat*20+chb*5+ks][lane][8 shorts]: 40*64*16B = 40 KB
    __shared__ __align__(16) unsigned short Bl[40 * 64 * 8];

    const int tid = threadIdx.x;
    const int lane = tid & 63, lr = lane & 15, lq = lane >> 4;

    // one-time B stage (frag-major so hot-loop reads are lane*16B = conflict-free)
    for (int j = tid; j < 40 * 64; j += 256) {
        int f = j >> 6, ls = j & 63;
        int lq2 = ls >> 4, lr2 = ls & 15;
        int mat = f / 20, rem = f - mat * 20, chb = rem / 5, ks = rem - chb * 5;
        bf16x8 v = *(const bf16x8*)(wb + (size_t)(mat * 64 + chb * 16 + lr2) * 160 + ks * 32 + lq2 * 8);
        *(bf16x8*)&Bl[(size_t)j * 8] = v;
    }
    __syncthreads();  // only barrier in the kernel

    float biasF[4], biasS[4];
    #pragma unroll
    for (int chb = 0; chb < 4; ++chb) {
        biasF[chb] = bfv[chb * 16 + lr];
        biasS[chb] = bsv[chb * 16 + lr];
    }

    const int NT16 = N_EDGES / 16;           // 100000 wave-tiles
    const int wg = blockIdx.x * 4 + (tid >> 6);
    const int wstride = gridDim.x * 4;
    const int lq4 = lq * 4;

    for (int T = wg; T < NT16; T += wstride) {
        const int e0 = T * 16;
        int2 sd = sed[e0 + lr];              // dst/src for this lane's edge (lr)
        const int dme = sd.y, sme = sd.x;
        const int eix = eidx[e0 + lr];

        // ---- A-frags direct to registers ----
        bf16x8 ad0 = *(const bf16x8*)(xb + (size_t)dme * 64 + lq * 8);
        bf16x8 ad1 = *(const bf16x8*)(xb + (size_t)dme * 64 + 32 + lq * 8);
        bf16x8 as0 = *(const bf16x8*)(xb + (size_t)sme * 64 + lq * 8);
        bf16x8 as1 = *(const bf16x8*)(xb + (size_t)sme * 64 + 32 + lq * 8);
        // edge_attr: f32 gather (4 lanes cover one 128B row line), convert to bf16
        float4 ev0 = *(const float4*)(ea + (size_t)eix * 32 + lq * 8);
        float4 ev1 = *(const float4*)(ea + (size_t)eix * 32 + lq * 8 + 4);
        bf16x8 ae;
        ae[0] = (short)f2b(ev0.x); ae[1] = (short)f2b(ev0.y);
        ae[2] = (short)f2b(ev0.z); ae[3] = (short)f2b(ev0.w);
        ae[4] = (short)f2b(ev1.x); ae[5] = (short)f2b(ev1.y);
        ae[6] = (short)f2b(ev1.z); ae[7] = (short)f2b(ev1.w);

        // ---- 40 MFMA, B from LDS (frag-major, 16B/lane stride) ----
        f32x4 aF[4] = {}; f32x4 aS[4] = {};
        #pragma unroll
        for (int ks = 0; ks < 5; ++ks) {
            bf16x8 a = (ks == 0) ? ad0 : (ks == 1) ? ad1 : (ks == 2) ? as0 : (ks == 3) ? as1 : ae;
            #pragma unroll
            for (int chb = 0; chb < 4; ++chb) {
                bf16x8 b0 = *(const bf16x8*)&Bl[(size_t)((0 * 20 + chb * 5 + ks) * 64 + lane) * 8];
                bf16x8 b1 = *(const bf16x8*)&Bl[(size_t)((1 * 20 + chb * 5 + ks) * 64 + lane) * 8];
                aF[chb] = __builtin_amdgcn_mfma_f32_16x16x32_bf16(a, b0, aF[chb], 0, 0, 0);
                aS[chb] = __builtin_amdgcn_mfma_f32_16x16x32_bf16(a, b1, aS[chb], 0, 0, 0);
            }
        }

        // ---- activation in registers: val[chb][i], edge = lq*4+i, ch = chb*16+lr ----
        float val[16];
        #pragma unroll
        for (int chb = 0; chb < 4; ++chb)
            #pragma unroll
            for (int i = 0; i < 4; ++i) {
                float f = aF[chb][i] + biasF[chb];
                float s = aS[chb][i] + biasS[chb];
                float sig = RCPF(1.0f + __expf(-f));
                float sp = fmaxf(s, 0.0f) + __logf(1.0f + __expf(-fabsf(s)));
                val[chb * 4 + i] = sig * sp;
            }

        // ---- run-reduction over the 16 edges (dst-sorted) ----
        {
            int dprev = __shfl(dme, lane - 1);
            unsigned long long bmask = __ballot((lr == 0) || (dme != dprev)) & 0xFFFFull;
            while (bmask) {
                int lo = (int)__builtin_ctzll(bmask);
                bmask &= bmask - 1;
                int hi = bmask ? (int)__builtin_ctzll(bmask) : 16;
                int dst = __shfl(dme, lo);     // wave-uniform
                float tc[4];
                #pragma unroll
                for (int chb = 0; chb < 4; ++chb) {
                    float s = 0.0f;
                    #pragma unroll
                    for (int i = 0; i < 4; ++i) {
                        int r = lq4 + i;
                        s += ((r >= lo) && (r < hi)) ? val[chb * 4 + i] : 0.0f;
                    }
                    s += __shfl_xor(s, 16);
                    s += __shfl_xor(s, 32);    // butterfly: sum lands in ALL lanes
                    tc[chb] = s;
                }
                float tsel = (lq == 0) ? tc[0] : (lq == 1) ? tc[1] : (lq == 2) ? tc[2] : tc[3];
                atomicAdd(&agg[(size_t)dst * 64 + lq * 16 + lr], tsel);  // one 64-lane atomic/run
            }
        }
    }
}

// ---------------- residual: hb = bf16(agg*inv_deg + x) ----------------
__global__ void resid2_kernel(const float4* __restrict__ agg, const float* __restrict__ inv_deg,
                              const float4* __restrict__ x, unsigned short* __restrict__ hb)
{
    int i = blockIdx.x * 256 + threadIdx.x;
    if (i >= N_NODES * 16) return;
    int n = i >> 4;
    float iv = inv_deg[n];
    float4 a = agg[i], xv = x[i];
    ushort4 u;
    u.x = f2b(a.x * iv + xv.x); u.y = f2b(a.y * iv + xv.y);
    u.z = f2b(a.z * iv + xv.z); u.w = f2b(a.w * iv + xv.w);
    *(ushort4*)(hb + i * 4) = u;
}

// ---------------- layer-2 residual + pooling: run-reduction over SORTED batch ----------------
__global__ void pool2_kernel(const float* __restrict__ agg, const float* __restrict__ inv_deg,
                             const unsigned short* __restrict__ hb, const int* __restrict__ batch,
                             float* __restrict__ gsum, float* __restrict__ gcnt)
{
    const int ch = threadIdx.x & 63, sub = threadIdx.x >> 6;
    const int base = blockIdx.x * 64 + sub * 16;
    float acc = 0.0f;
    int gcur = -1, rl = 0;
    #pragma unroll
    for (int j = 0; j < 16; ++j) {
        int n = base + j;
        if (n >= N_NODES) break;
        int g = batch[n];
        float v = agg[(size_t)n * 64 + ch] * inv_deg[n] + b2f(hb[(size_t)n * 64 + ch]);
        if (g != gcur) {
            if (gcur >= 0) {
                atomicAdd(&gsum[gcur * 64 + ch], acc);
                if (ch == 0) atomicAdd(&gcnt[gcur], (float)rl);
            }
            gcur = g; acc = v; rl = 1;
        } else {
            acc += v; rl++;
        }
    }
    if (gcur >= 0) {
        atomicAdd(&gsum[gcur * 64 + ch], acc);
        if (ch == 0) atomicAdd(&gcnt[gcur], (float)rl);
    }
}

// ---------------- head: MLP + log_softmax ----------------
__global__ __launch_bounds__(64)
void head_kernel(const float* __restrict__ gsum, const float* __restrict__ gcnt,
                 const float* __restrict__ w1, const float* __restrict__ b1,
                 const float* __restrict__ w2, const float* __restrict__ b2,
                 float* __restrict__ out)
{
    __shared__ float gv[64];
    __shared__ float hid[256];
    __shared__ float outv[16];
    const int g = blockIdx.x, t = threadIdx.x;
    float cnt = fmaxf(gcnt[g], 1.0f);
    gv[t] = gsum[g * 64 + t] / cnt;
    __syncthreads();
    #pragma unroll
    for (int r = 0; r < 4; ++r) {
        int c = t + r * 64;
        float acc = b1[c];
        const float4* wr = (const float4*)(w1 + c * 64);
        const float4* gvv = (const float4*)gv;
        #pragma unroll
        for (int k = 0; k < 16; ++k) {
            float4 wv = wr[k], xv = gvv[k];
            acc += wv.x * xv.x + wv.y * xv.y + wv.z * xv.z + wv.w * xv.w;
        }
        hid[c] = fmaxf(acc, 0.0f);
    }
    __syncthreads();
    if (t < 16) {
        float acc = b2[t];
        const float4* wr = (const float4*)(w2 + t * 256);
        const float4* hv = (const float4*)hid;
        for (int k = 0; k < 64; ++k) {
            float4 wv = wr[k], xv = hv[k];
            acc += wv.x * xv.x + wv.y * xv.y + wv.z * xv.z + wv.w * xv.w;
        }
        outv[t] = acc;
    }
    __syncthreads();
    if (t < 16) {
        float m = outv[0];
        #pragma unroll
        for (int j = 1; j < 16; ++j) m = fmaxf(m, outv[j]);
        float ssum = 0.0f;
        #pragma unroll
        for (int j = 0; j < 16; ++j) ssum += expf(outv[j] - m);
        out[g * 16 + t] = outv[t] - m - logf(ssum);
    }
}

extern "C" void kernel_launch(void* const* d_in, const int* in_sizes, int n_in,
                              void* d_out, int out_size, void* d_ws, size_t ws_size,
                              hipStream_t stream)
{
    const float* x     = (const float*)d_in[0];
    const int*   ei    = (const int*)d_in[1];
    const float* ea    = (const float*)d_in[2];
    const int*   batch = (const int*)d_in[3];
    const float* wf1 = (const float*)d_in[4];
    const float* bf1 = (const float*)d_in[5];
    const float* ws1 = (const float*)d_in[6];
    const float* bs1 = (const float*)d_in[7];
    const float* wf2 = (const float*)d_in[8];
    const float* bf2 = (const float*)d_in[9];
    const float* ws2 = (const float*)d_in[10];
    const float* bs2 = (const float*)d_in[11];
    const float* w1 = (const float*)d_in[12];
    const float* b1 = (const float*)d_in[13];
    const float* w2 = (const float*)d_in[14];
    const float* b2 = (const float*)d_in[15];
    float* out = (float*)d_out;

    char* ws = (char*)d_ws;
    int*   cnt    = (int*)(ws + 0x0000000);           // 200 KB
    int*   cursor = (int*)(ws + 0x0040000);           // 200 KB
    float* invdeg = (float*)(ws + 0x0080000);         // 200 KB
    int*   bsum   = (int*)(ws + 0x00C0000);           // 1 KB
    int*   boffs  = (int*)(ws + 0x00C1000);           // 1 KB
    int2*  sed    = (int2*)(ws + 0x0100000);          // 12.8 MB
    int*   eidx   = (int*)(ws + 0x0E00000);           // 6.4 MB
    unsigned short* xb  = (unsigned short*)(ws + 0x1500000);  // 6.4 MB
    unsigned short* hb  = (unsigned short*)(ws + 0x1C00000);  // 6.4 MB
    float* agg = (float*)(ws + 0x2300000);            // 12.8 MB
    unsigned short* wb1 = (unsigned short*)(ws + 0x3000000);  // 40 KB
    unsigned short* wb2 = (unsigned short*)(ws + 0x3010000);  // 40 KB
    float* gsum = (float*)(ws + 0x3020000);           // 128 KB
    float* gcnt = (float*)(ws + 0x3040000);           // 2 KB

    hipMemsetAsync(cnt, 0, 200000, stream);
    hipMemsetAsync(agg, 0, 12800000, stream);
    hipMemsetAsync(gsum, 0, 131072 + 2048, stream);

    prep_w_kernel<<<80, 256, 0, stream>>>(wf1, ws1, wf2, ws2, wb1, wb2);
    prep_x_kernel<<<3125, 256, 0, stream>>>((const float4*)x, xb);
    hist_kernel<<<6250, 256, 0, stream>>>(ei, cnt);
    bsum_kernel<<<NBS, 256, 0, stream>>>(cnt, bsum);
    bscan_kernel<<<1, 256, 0, stream>>>(bsum, boffs);
    apply_kernel<<<NBS, 256, 0, stream>>>(cnt, boffs, cursor, invdeg);
    scatter_kernel<<<6250, 256, 0, stream>>>(ei, cursor, sed, eidx);

    edge_mfma<<<1024, 256, 0, stream>>>(xb, sed, eidx, ea, wb1, bf1, bs1, agg);
    resid2_kernel<<<3125, 256, 0, stream>>>((const float4*)agg, invdeg, (const float4*)x, hb);
    hipMemsetAsync(agg, 0, 12800000, stream);
    edge_mfma<<<1024, 256, 0, stream>>>(hb, sed, eidx, ea, wb2, bf2, bs2, agg);
    pool2_kernel<<<782, 256, 0, stream>>>(agg, invdeg, hb, batch, gsum, gcnt);
    head_kernel<<<NUM_GRAPHS, 64, 0, stream>>>(gsum, gcnt, w1, b1, w2, b2, out);
}

// Round 19
// 509.036 us; speedup vs baseline: 1.2169x; 1.2169x over previous
//
#include <hip/hip_runtime.h>
#include <hip/hip_bf16.h>

#define N_NODES 50000
#define N_EDGES 1600000
#define IN_CH 64
#define NUM_HID 256
#define NUM_CLASSES 16
#define NUM_GRAPHS 512
#define NBS 196  // ceil(N_NODES/256)

typedef short bf16x8 __attribute__((ext_vector_type(8)));
typedef float f32x4 __attribute__((ext_vector_type(4)));

#if __has_builtin(__builtin_amdgcn_rcpf)
#define RCPF(x) __builtin_amdgcn_rcpf(x)
#else
#define RCPF(x) (1.0f / (x))
#endif

__device__ inline unsigned short f2b(float f) {
    unsigned int u = __float_as_uint(f);
    unsigned int r = (u + 0x7FFF + ((u >> 16) & 1)) >> 16;
    return (unsigned short)r;
}
__device__ inline float b2f(unsigned short u) {
    return __uint_as_float(((unsigned int)u) << 16);
}

// ---------------- preprocessing ----------------
__global__ void prep_w_kernel(const float* __restrict__ wf1, const float* __restrict__ ws1,
                              const float* __restrict__ wf2, const float* __restrict__ ws2,
                              unsigned short* __restrict__ wb1, unsigned short* __restrict__ wb2) {
    int i = blockIdx.x * 256 + threadIdx.x;
    if (i >= 128 * 160) return;
    int r = i / 160, k = i - r * 160;
    wb1[i] = f2b(r < 64 ? wf1[r * 160 + k] : ws1[(r - 64) * 160 + k]);
    wb2[i] = f2b(r < 64 ? wf2[r * 160 + k] : ws2[(r - 64) * 160 + k]);
}

__global__ void prep_x_kernel(const float4* __restrict__ x, unsigned short* __restrict__ xb) {
    int i = blockIdx.x * 256 + threadIdx.x;
    if (i >= N_NODES * 16) return;
    float4 v = x[i];
    ushort4 u; u.x = f2b(v.x); u.y = f2b(v.y); u.z = f2b(v.z); u.w = f2b(v.w);
    *(ushort4*)(xb + i * 4) = u;
}

__global__ void hist_kernel(const int* __restrict__ ei, int* __restrict__ cnt) {
    int i = blockIdx.x * 256 + threadIdx.x;
    if (i < N_EDGES) atomicAdd(&cnt[ei[N_EDGES + i]], 1);
}

__global__ void bsum_kernel(const int* __restrict__ cnt, int* __restrict__ bsum) {
    __shared__ int sm[256];
    int i = blockIdx.x * 256 + threadIdx.x;
    sm[threadIdx.x] = (i < N_NODES) ? cnt[i] : 0;
    __syncthreads();
    for (int off = 128; off > 0; off >>= 1) {
        if (threadIdx.x < off) sm[threadIdx.x] += sm[threadIdx.x + off];
        __syncthreads();
    }
    if (threadIdx.x == 0) bsum[blockIdx.x] = sm[0];
}

__global__ void bscan_kernel(const int* __restrict__ bsum, int* __restrict__ boffs) {
    __shared__ int sm[256];
    int t = threadIdx.x;
    int v = (t < NBS) ? bsum[t] : 0;
    sm[t] = v; __syncthreads();
    for (int off = 1; off < 256; off <<= 1) {
        int u = (t >= off) ? sm[t - off] : 0;
        __syncthreads();
        sm[t] += u;
        __syncthreads();
    }
    if (t < NBS) boffs[t] = sm[t] - v;  // exclusive
}

__global__ void apply_kernel(const int* __restrict__ cnt, const int* __restrict__ boffs,
                             int* __restrict__ cursor, float* __restrict__ invdeg) {
    __shared__ int sm[256];
    int t = threadIdx.x, i = blockIdx.x * 256 + t;
    int c = (i < N_NODES) ? cnt[i] : 0;
    sm[t] = c; __syncthreads();
    for (int off = 1; off < 256; off <<= 1) {
        int u = (t >= off) ? sm[t - off] : 0;
        __syncthreads();
        sm[t] += u;
        __syncthreads();
    }
    if (i < N_NODES) {
        cursor[i] = boffs[blockIdx.x] + sm[t] - c;
        invdeg[i] = 1.0f / fmaxf((float)c, 1.0f);
    }
}

// scatter + in-place sort of edge_attr to dst-order (bf16), fused (r17 proven)
__global__ void scatter_kernel(const int* __restrict__ ei, int* __restrict__ cursor,
                               const float* __restrict__ ea,
                               int2* __restrict__ sed, unsigned short* __restrict__ eab) {
    int e = blockIdx.x * 256 + threadIdx.x;
    if (e >= N_EDGES) return;
    int s = ei[e], d = ei[N_EDGES + e];
    int p = atomicAdd(&cursor[d], 1);
    sed[p] = make_int2(s, d);
    const float4* src = (const float4*)(ea + (size_t)e * 32);
    unsigned short* dst = eab + (size_t)p * 32;
    #pragma unroll
    for (int j = 0; j < 8; ++j) {
        float4 v = src[j];
        ushort4 u; u.x = f2b(v.x); u.y = f2b(v.y); u.z = f2b(v.z); u.w = f2b(v.w);
        *(ushort4*)(dst + j * 4) = u;
    }
}

// ---------------- edge pass: WAVE-PRIVATE 16-edge tiles + next-tile prefetch ----------------
// B in LDS frag-major (read-only). Per tile: prefetch T+1's sed/eab at top (land during
// MFMA), issue T+1's xb gathers after MFMA (land during act+reduce) -> gather latency
// fully hidden. Ballot run-reduce -> one 64-lane atomic per run. No main-loop barriers.
__global__ __launch_bounds__(256, 2)
void edge_mfma(const unsigned short* __restrict__ xb,
               const int2* __restrict__ sed, const unsigned short* __restrict__ eab,
               const unsigned short* __restrict__ wb,
               const float* __restrict__ bfv, const float* __restrict__ bsv,
               float* __restrict__ agg)
{
    // Bl[frag=mat*20+chb*5+ks][lane][8 shorts]: 40*64*16B = 40 KB
    __shared__ __align__(16) unsigned short Bl[40 * 64 * 8];

    const int tid = threadIdx.x;
    const int lane = tid & 63, lr = lane & 15, lq = lane >> 4;

    // one-time B stage (frag-major so hot-loop reads are lane*16B = conflict-free)
    for (int j = tid; j < 40 * 64; j += 256) {
        int f = j >> 6, ls = j & 63;
        int lq2 = ls >> 4, lr2 = ls & 15;
        int mat = f / 20, rem = f - mat * 20, chb = rem / 5, ks = rem - chb * 5;
        bf16x8 v = *(const bf16x8*)(wb + (size_t)(mat * 64 + chb * 16 + lr2) * 160 + ks * 32 + lq2 * 8);
        *(bf16x8*)&Bl[(size_t)j * 8] = v;
    }
    __syncthreads();  // only barrier in the kernel

    float biasF[4], biasS[4];
    #pragma unroll
    for (int chb = 0; chb < 4; ++chb) {
        biasF[chb] = bfv[chb * 16 + lr];
        biasS[chb] = bsv[chb * 16 + lr];
    }

    const int NT16 = N_EDGES / 16;           // 100000 wave-tiles
    const int wg = blockIdx.x * 4 + (tid >> 6);
    const int wstride = gridDim.x * 4;
    const int lq4 = lq * 4;

    // ---- preamble: load tile wg's operands ----
    int2 sd; bf16x8 ad0, ad1, as0, as1, ae;
    int T = wg;
    if (T < NT16) {
        sd = sed[T * 16 + lr];
        ae = *(const bf16x8*)(eab + (size_t)(T * 16 + lr) * 32 + lq * 8);
        ad0 = *(const bf16x8*)(xb + (size_t)sd.y * 64 + lq * 8);
        ad1 = *(const bf16x8*)(xb + (size_t)sd.y * 64 + 32 + lq * 8);
        as0 = *(const bf16x8*)(xb + (size_t)sd.x * 64 + lq * 8);
        as1 = *(const bf16x8*)(xb + (size_t)sd.x * 64 + 32 + lq * 8);
    }

    for (; T < NT16; T += wstride) {
        const int Tn = T + wstride;
        const bool pf = Tn < NT16;
        int2 nsd; bf16x8 nae;
        if (pf) {   // prefetch next tile's indices + edge_attr (land during MFMA)
            nsd = sed[Tn * 16 + lr];
            nae = *(const bf16x8*)(eab + (size_t)(Tn * 16 + lr) * 32 + lq * 8);
        }

        const int dme = sd.y;

        // ---- 40 MFMA, B from LDS (frag-major, 16B/lane stride) ----
        f32x4 aF[4] = {}; f32x4 aS[4] = {};
        #pragma unroll
        for (int ks = 0; ks < 5; ++ks) {
            bf16x8 a = (ks == 0) ? ad0 : (ks == 1) ? ad1 : (ks == 2) ? as0 : (ks == 3) ? as1 : ae;
            #pragma unroll
            for (int chb = 0; chb < 4; ++chb) {
                bf16x8 b0 = *(const bf16x8*)&Bl[(size_t)((0 * 20 + chb * 5 + ks) * 64 + lane) * 8];
                bf16x8 b1 = *(const bf16x8*)&Bl[(size_t)((1 * 20 + chb * 5 + ks) * 64 + lane) * 8];
                aF[chb] = __builtin_amdgcn_mfma_f32_16x16x32_bf16(a, b0, aF[chb], 0, 0, 0);
                aS[chb] = __builtin_amdgcn_mfma_f32_16x16x32_bf16(a, b1, aS[chb], 0, 0, 0);
            }
        }

        // ---- issue next tile's x/h gathers (nsd ready; land during act+reduce) ----
        bf16x8 nad0, nad1, nas0, nas1;
        if (pf) {
            nad0 = *(const bf16x8*)(xb + (size_t)nsd.y * 64 + lq * 8);
            nad1 = *(const bf16x8*)(xb + (size_t)nsd.y * 64 + 32 + lq * 8);
            nas0 = *(const bf16x8*)(xb + (size_t)nsd.x * 64 + lq * 8);
            nas1 = *(const bf16x8*)(xb + (size_t)nsd.x * 64 + 32 + lq * 8);
        }

        // ---- activation in registers: val[chb][i], edge = lq*4+i, ch = chb*16+lr ----
        float val[16];
        #pragma unroll
        for (int chb = 0; chb < 4; ++chb)
            #pragma unroll
            for (int i = 0; i < 4; ++i) {
                float f = aF[chb][i] + biasF[chb];
                float s = aS[chb][i] + biasS[chb];
                float sig = RCPF(1.0f + __expf(-f));
                float sp = fmaxf(s, 0.0f) + __logf(1.0f + __expf(-fabsf(s)));
                val[chb * 4 + i] = sig * sp;
            }

        // ---- run-reduction over the 16 edges (dst-sorted) ----
        {
            int dprev = __shfl(dme, lane - 1);
            unsigned long long bmask = __ballot((lr == 0) || (dme != dprev)) & 0xFFFFull;
            while (bmask) {
                int lo = (int)__builtin_ctzll(bmask);
                bmask &= bmask - 1;
                int hi = bmask ? (int)__builtin_ctzll(bmask) : 16;
                int dst = __shfl(dme, lo);     // wave-uniform
                float tc[4];
                #pragma unroll
                for (int chb = 0; chb < 4; ++chb) {
                    float s = 0.0f;
                    #pragma unroll
                    for (int i = 0; i < 4; ++i) {
                        int r = lq4 + i;
                        s += ((r >= lo) && (r < hi)) ? val[chb * 4 + i] : 0.0f;
                    }
                    s += __shfl_xor(s, 16);
                    s += __shfl_xor(s, 32);    // butterfly: sum lands in ALL lanes
                    tc[chb] = s;
                }
                float tsel = (lq == 0) ? tc[0] : (lq == 1) ? tc[1] : (lq == 2) ? tc[2] : tc[3];
                atomicAdd(&agg[(size_t)dst * 64 + lq * 16 + lr], tsel);  // one 64-lane atomic/run
            }
        }

        // ---- rotate prefetched operands into place ----
        if (pf) {
            sd = nsd; ae = nae;
            ad0 = nad0; ad1 = nad1; as0 = nas0; as1 = nas1;
        }
    }
}

// ---------------- residual: hb = bf16(agg*inv_deg + x) ----------------
__global__ void resid2_kernel(const float4* __restrict__ agg, const float* __restrict__ inv_deg,
                              const float4* __restrict__ x, unsigned short* __restrict__ hb)
{
    int i = blockIdx.x * 256 + threadIdx.x;
    if (i >= N_NODES * 16) return;
    int n = i >> 4;
    float iv = inv_deg[n];
    float4 a = agg[i], xv = x[i];
    ushort4 u;
    u.x = f2b(a.x * iv + xv.x); u.y = f2b(a.y * iv + xv.y);
    u.z = f2b(a.z * iv + xv.z); u.w = f2b(a.w * iv + xv.w);
    *(ushort4*)(hb + i * 4) = u;
}

// ---------------- layer-2 residual + pooling: run-reduction over SORTED batch ----------------
__global__ void pool2_kernel(const float* __restrict__ agg, const float* __restrict__ inv_deg,
                             const unsigned short* __restrict__ hb, const int* __restrict__ batch,
                             float* __restrict__ gsum, float* __restrict__ gcnt)
{
    const int ch = threadIdx.x & 63, sub = threadIdx.x >> 6;
    const int base = blockIdx.x * 64 + sub * 16;
    float acc = 0.0f;
    int gcur = -1, rl = 0;
    #pragma unroll
    for (int j = 0; j < 16; ++j) {
        int n = base + j;
        if (n >= N_NODES) break;
        int g = batch[n];
        float v = agg[(size_t)n * 64 + ch] * inv_deg[n] + b2f(hb[(size_t)n * 64 + ch]);
        if (g != gcur) {
            if (gcur >= 0) {
                atomicAdd(&gsum[gcur * 64 + ch], acc);
                if (ch == 0) atomicAdd(&gcnt[gcur], (float)rl);
            }
            gcur = g; acc = v; rl = 1;
        } else {
            acc += v; rl++;
        }
    }
    if (gcur >= 0) {
        atomicAdd(&gsum[gcur * 64 + ch], acc);
        if (ch == 0) atomicAdd(&gcnt[gcur], (float)rl);
    }
}

// ---------------- head: MLP + log_softmax ----------------
__global__ __launch_bounds__(64)
void head_kernel(const float* __restrict__ gsum, const float* __restrict__ gcnt,
                 const float* __restrict__ w1, const float* __restrict__ b1,
                 const float* __restrict__ w2, const float* __restrict__ b2,
                 float* __restrict__ out)
{
    __shared__ float gv[64];
    __shared__ float hid[256];
    __shared__ float outv[16];
    const int g = blockIdx.x, t = threadIdx.x;
    float cnt = fmaxf(gcnt[g], 1.0f);
    gv[t] = gsum[g * 64 + t] / cnt;
    __syncthreads();
    #pragma unroll
    for (int r = 0; r < 4; ++r) {
        int c = t + r * 64;
        float acc = b1[c];
        const float4* wr = (const float4*)(w1 + c * 64);
        const float4* gvv = (const float4*)gv;
        #pragma unroll
        for (int k = 0; k < 16; ++k) {
            float4 wv = wr[k], xv = gvv[k];
            acc += wv.x * xv.x + wv.y * xv.y + wv.z * xv.z + wv.w * xv.w;
        }
        hid[c] = fmaxf(acc, 0.0f);
    }
    __syncthreads();
    if (t < 16) {
        float acc = b2[t];
        const float4* wr = (const float4*)(w2 + t * 256);
        const float4* hv = (const float4*)hid;
        for (int k = 0; k < 64; ++k) {
            float4 wv = wr[k], xv = hv[k];
            acc += wv.x * xv.x + wv.y * xv.y + wv.z * xv.z + wv.w * xv.w;
        }
        outv[t] = acc;
    }
    __syncthreads();
    if (t < 16) {
        float m = outv[0];
        #pragma unroll
        for (int j = 1; j < 16; ++j) m = fmaxf(m, outv[j]);
        float ssum = 0.0f;
        #pragma unroll
        for (int j = 0; j < 16; ++j) ssum += expf(outv[j] - m);
        out[g * 16 + t] = outv[t] - m - logf(ssum);
    }
}

extern "C" void kernel_launch(void* const* d_in, const int* in_sizes, int n_in,
                              void* d_out, int out_size, void* d_ws, size_t ws_size,
                              hipStream_t stream)
{
    const float* x     = (const float*)d_in[0];
    const int*   ei    = (const int*)d_in[1];
    const float* ea    = (const float*)d_in[2];
    const int*   batch = (const int*)d_in[3];
    const float* wf1 = (const float*)d_in[4];
    const float* bf1 = (const float*)d_in[5];
    const float* ws1 = (const float*)d_in[6];
    const float* bs1 = (const float*)d_in[7];
    const float* wf2 = (const float*)d_in[8];
    const float* bf2 = (const float*)d_in[9];
    const float* ws2 = (const float*)d_in[10];
    const float* bs2 = (const float*)d_in[11];
    const float* w1 = (const float*)d_in[12];
    const float* b1 = (const float*)d_in[13];
    const float* w2 = (const float*)d_in[14];
    const float* b2 = (const float*)d_in[15];
    float* out = (float*)d_out;

    char* ws = (char*)d_ws;
    int*   cnt    = (int*)(ws + 0x0000000);           // 200 KB
    int*   cursor = (int*)(ws + 0x0040000);           // 200 KB
    float* invdeg = (float*)(ws + 0x0080000);         // 200 KB
    int*   bsum   = (int*)(ws + 0x00C0000);           // 1 KB
    int*   boffs  = (int*)(ws + 0x00C1000);           // 1 KB
    int2*  sed    = (int2*)(ws + 0x0100000);          // 12.8 MB
    unsigned short* xb  = (unsigned short*)(ws + 0x1500000);  // 6.4 MB
    unsigned short* hb  = (unsigned short*)(ws + 0x1C00000);  // 6.4 MB
    float* agg = (float*)(ws + 0x2300000);            // 12.8 MB
    unsigned short* wb1 = (unsigned short*)(ws + 0x3000000);  // 40 KB
    unsigned short* wb2 = (unsigned short*)(ws + 0x3010000);  // 40 KB
    float* gsum = (float*)(ws + 0x3020000);           // 128 KB
    float* gcnt = (float*)(ws + 0x3040000);           // 2 KB
    unsigned short* eab = (unsigned short*)(ws + 0x3100000);  // 102.4 MB (fits: r8-r17 ran this)

    hipMemsetAsync(cnt, 0, 200000, stream);
    hipMemsetAsync(agg, 0, 12800000, stream);
    hipMemsetAsync(gsum, 0, 131072 + 2048, stream);

    prep_w_kernel<<<80, 256, 0, stream>>>(wf1, ws1, wf2, ws2, wb1, wb2);
    prep_x_kernel<<<3125, 256, 0, stream>>>((const float4*)x, xb);
    hist_kernel<<<6250, 256, 0, stream>>>(ei, cnt);
    bsum_kernel<<<NBS, 256, 0, stream>>>(cnt, bsum);
    bscan_kernel<<<1, 256, 0, stream>>>(bsum, boffs);
    apply_kernel<<<NBS, 256, 0, stream>>>(cnt, boffs, cursor, invdeg);
    scatter_kernel<<<6250, 256, 0, stream>>>(ei, cursor, ea, sed, eab);

    edge_mfma<<<1024, 256, 0, stream>>>(xb, sed, eab, wb1, bf1, bs1, agg);
    resid2_kernel<<<3125, 256, 0, stream>>>((const float4*)agg, invdeg, (const float4*)x, hb);
    hipMemsetAsync(agg, 0, 12800000, stream);
    edge_mfma<<<1024, 256, 0, stream>>>(hb, sed, eab, wb2, bf2, bs2, agg);
    pool2_kernel<<<782, 256, 0, stream>>>(agg, invdeg, hb, batch, gsum, gcnt);
    head_kernel<<<NUM_GRAPHS, 64, 0, stream>>>(gsum, gcnt, w1, b1, w2, b2, out);
}